// Round 1
// 292.657 us; speedup vs baseline: 1.1471x; 1.1471x over previous
//
#include <hip/hip_runtime.h>

#define Bn 32
#define Cc 128
#define Nn 307
#define Ll 12
#define LH 13
#define LAYERS 4
#define BN_EPS 1e-5f
#define SCW (Cc + 1)  // padded LDS stride to kill bank conflicts

// ============================================================================
// G1[ch][l][b][t0][n] = sum_c X[b,c,n,t] * c1[l,c]
// grid (10 ntiles, 32 b, 2 ch), block 256 = 8 c-chunks(16c) x 32 n
// Vectorized float4 x3 over contiguous t; LDS cross-chunk reduce.
// ============================================================================
__global__ __launch_bounds__(256) void k_g1(const float* __restrict__ XL,
                                            const float* __restrict__ XH,
                                            const float* __restrict__ lc1,
                                            const float* __restrict__ hc1,
                                            float* __restrict__ G1) {
    __shared__ float s_c1[LAYERS * Cc];
    __shared__ float sred[48 * 257];  // [j][tid], stride 257 -> conflict-free
    int tile = blockIdx.x;  // 0..9
    int b = blockIdx.y;
    int ch = blockIdx.z;
    const float* X = ch ? XH : XL;
    const float* c1 = ch ? hc1 : lc1;
    int tid = threadIdx.x;
    for (int j = tid; j < LAYERS * Cc; j += 256) s_c1[j] = c1[j];
    __syncthreads();
    int nl = tid & 31;
    int chunk = tid >> 5;  // 0..7, 16 c each
    int n = tile * 32 + nl;
    float acc[48];
#pragma unroll
    for (int j = 0; j < 48; ++j) acc[j] = 0.f;
    if (n < Nn) {
        const float* px = X + ((size_t)(b * Cc + chunk * 16) * Nn + n) * Ll;
#pragma unroll 2
        for (int i = 0; i < 16; ++i) {
            float4 v0 = *(const float4*)(px);
            float4 v1 = *(const float4*)(px + 4);
            float4 v2 = *(const float4*)(px + 8);
            float xv[12] = {v0.x, v0.y, v0.z, v0.w, v1.x, v1.y,
                            v1.z, v1.w, v2.x, v2.y, v2.z, v2.w};
            int c = chunk * 16 + i;
#pragma unroll
            for (int l = 0; l < LAYERS; ++l) {
                float wv = s_c1[l * Cc + c];
#pragma unroll
                for (int t = 0; t < 12; ++t) acc[l * 12 + t] += xv[t] * wv;
            }
            px += (size_t)Nn * Ll;
        }
    }
#pragma unroll
    for (int j = 0; j < 48; ++j) sred[j * 257 + tid] = acc[j];
    __syncthreads();
    size_t cb = (size_t)ch * LAYERS * Bn * (LH * Nn);
    for (int o = tid; o < 1536; o += 256) {  // 32 nl x 48 j
        int onl = o & 31, j = o >> 5;
        float v = 0.f;
#pragma unroll
        for (int k = 0; k < 8; ++k) v += sred[j * 257 + k * 32 + onl];
        int nn = tile * 32 + onl;
        if (nn < Nn) {
            int l = j / 12, t = j % 12;
            int t0 = ch ? (t + 1) : t;  // high channel shifted by left-pad
            G1[cb + ((size_t)l * Bn + b) * (LH * Nn) + (size_t)t0 * Nn + nn] = v;
        }
    }
    if (ch && tid < 128) {  // zero plane t0=0 for high channel
        int l = tid >> 5, onl = tid & 31;
        int nn = tile * 32 + onl;
        if (nn < Nn) G1[cb + ((size_t)l * Bn + b) * (LH * Nn) + nn] = 0.f;
    }
}

// ============================================================================
// G2[ch][l][b][t0][c] = sum_n X[b,c,n,t] * c2[l,n]
// grid (32 ctiles, 32 b, 2 ch), block 256 = 4 waves (one c each), lanes span n.
// Coalesced 3 KB/wave loads; per-wave LDS reduce over 64 lanes.
// ============================================================================
__global__ __launch_bounds__(256) void k_g2(const float* __restrict__ XL,
                                            const float* __restrict__ XH,
                                            const float* __restrict__ lc2,
                                            const float* __restrict__ hc2,
                                            float* __restrict__ G2) {
    __shared__ float s_c2[LAYERS * Nn];
    __shared__ float sred[4 * 48 * 65];  // [w][j][lane], stride 65
    int ctile = blockIdx.x;  // 0..31 (4 c each)
    int b = blockIdx.y;
    int ch = blockIdx.z;
    const float* X = ch ? XH : XL;
    const float* c2 = ch ? hc2 : lc2;
    int tid = threadIdx.x;
    for (int j = tid; j < LAYERS * Nn; j += 256) s_c2[j] = c2[j];
    __syncthreads();
    int w = tid >> 6, lane = tid & 63;
    int c = ctile * 4 + w;
    float acc[48];
#pragma unroll
    for (int j = 0; j < 48; ++j) acc[j] = 0.f;
    const float* pb = X + (size_t)(b * Cc + c) * Nn * Ll;
    for (int k = 0; k < 5; ++k) {
        int n = k * 64 + lane;
        if (n < Nn) {
            const float* px = pb + (size_t)n * Ll;
            float4 v0 = *(const float4*)(px);
            float4 v1 = *(const float4*)(px + 4);
            float4 v2 = *(const float4*)(px + 8);
            float xv[12] = {v0.x, v0.y, v0.z, v0.w, v1.x, v1.y,
                            v1.z, v1.w, v2.x, v2.y, v2.z, v2.w};
#pragma unroll
            for (int l = 0; l < LAYERS; ++l) {
                float wv = s_c2[l * Nn + n];
#pragma unroll
                for (int t = 0; t < 12; ++t) acc[l * 12 + t] += xv[t] * wv;
            }
        }
    }
#pragma unroll
    for (int j = 0; j < 48; ++j) sred[(w * 48 + j) * 65 + lane] = acc[j];
    __syncthreads();
    size_t cb = (size_t)ch * LAYERS * Bn * (LH * Cc);
    if (tid < 192) {  // 4 w x 48 j outputs
        int ww = tid / 48, j = tid % 48;
        float v = 0.f;
        for (int k2 = 0; k2 < 64; ++k2) v += sred[(ww * 48 + j) * 65 + k2];
        int l = j / 12, t = j % 12;
        int t0 = ch ? (t + 1) : t;
        int cc2 = ctile * 4 + ww;
        G2[cb + ((size_t)l * Bn + b) * (LH * Cc) + (size_t)t0 * Cc + cc2] = v;
    } else if (ch && tid < 208) {  // zero plane t0=0 for high channel
        int r = tid - 192;
        int l = r >> 2, ww = r & 3;
        G2[cb + ((size_t)l * Bn + b) * (LH * Cc) + ctile * 4 + ww] = 0.f;
    }
}

// ---- per (ch,l,b): GW = G1*w, then M[t0][t1] = sum_c GW*G2 -> global (unchanged)
__global__ __launch_bounds__(256) void k_gwm(const float* __restrict__ lw,
                                             const float* __restrict__ hw,
                                             const float* __restrict__ G1,
                                             const float* __restrict__ G2,
                                             float* __restrict__ M) {
    __shared__ float sG1[LH * Nn];
    __shared__ float sAcc[2][LH * SCW];
    __shared__ float sG2[LH * SCW];
    int blk = blockIdx.x;  // (ch*LAYERS + l)*Bn + b
    int cl = blk / Bn;
    int l = cl % LAYERS;
    int ch = cl / LAYERS;
    int T = ch ? LH : Ll;
    const float* w = (ch ? hw : lw) + (size_t)l * Nn * Cc;
    const float* g1 = G1 + (size_t)blk * (LH * Nn);
    const float* g2 = G2 + (size_t)blk * (LH * Cc);
    int tid = threadIdx.x;
    for (int i = tid; i < LH * Nn; i += 256) sG1[i] = (i < T * Nn) ? g1[i] : 0.f;
    for (int i = tid; i < T * Cc; i += 256) sG2[(i / Cc) * SCW + (i % Cc)] = g2[i];
    __syncthreads();
    int half = tid >> 7;
    int c = tid & 127;
    float acc[LH];
#pragma unroll
    for (int t = 0; t < LH; ++t) acc[t] = 0.f;
    int n0 = half ? (Nn / 2) : 0;
    int n1 = half ? Nn : (Nn / 2);
    for (int n = n0; n < n1; ++n) {
        float wv = w[(size_t)n * Cc + c];
#pragma unroll
        for (int t = 0; t < LH; ++t) acc[t] += sG1[t * Nn + n] * wv;
    }
#pragma unroll
    for (int t = 0; t < LH; ++t) sAcc[half][t * SCW + c] = acc[t];
    __syncthreads();
    for (int i = tid; i < LH * Cc; i += 256) {
        int t = i / Cc, cc = i % Cc;
        sAcc[0][t * SCW + cc] += sAcc[1][t * SCW + cc];
    }
    __syncthreads();
    float* Mo = M + (size_t)blk * (LH * LH);
    for (int i = tid; i < T * T; i += 256) {
        int t0 = i / T, t1 = i % T;
        float a = 0.f;
        for (int cc = 0; cc < Cc; ++cc) a += sAcc[0][t0 * SCW + cc] * sG2[t1 * SCW + cc];
        Mo[t0 * LH + t1] = a;
    }
}

// ============================================================================
// Chain, split into 5 grid-wide launches (64 blocks = one per (ch,b)).
// Kernel boundaries provide the cross-b sync that BatchNorm needs.
// Stats[(l*2+ch)*2][q][b] : per-layer BN partials (sum, sumsq), no atomics.
// Lg[ch][b][.] : logits of current layer.  Pws[ch][b][.] : running P.
// ============================================================================

// layer-0 logits: with P=I, scores = sigmoid(bb + M), logits = v @ scores
template <int T>
__device__ __forceinline__ void first_impl(int ch, int b,
                                           const float* __restrict__ M,
                                           const float* __restrict__ bb,
                                           const float* __restrict__ v,
                                           float* __restrict__ Lg,
                                           float* __restrict__ Stats) {
    const int TT = T * T;
    __shared__ float sS[LH * LH];
    __shared__ float sA[LH * LH];
    int tid = threadIdx.x;
    const float* Ml = M + ((size_t)(ch * LAYERS + 0) * Bn + b) * (LH * LH);
    if (tid < TT) {
        int t = tid / T, q = tid % T;
        float a = bb[tid] + Ml[t * LH + q];
        sS[tid] = 1.f / (1.f + expf(-a));
    }
    __syncthreads();
    if (tid < TT) {
        int t = tid / T, q = tid % T;
        float a = 0.f;
#pragma unroll
        for (int k = 0; k < T; ++k) a += v[t * T + k] * sS[k * T + q];
        sA[tid] = a;
        Lg[(size_t)(ch * Bn + b) * (LH * LH) + tid] = a;
    }
    __syncthreads();
    if (tid < T) {
        float s = 0.f, ss = 0.f;
#pragma unroll
        for (int t = 0; t < T; ++t) {
            float x = sA[t * T + tid];
            s += x;
            ss += x * x;
        }
        float* St = Stats + (size_t)(0 * 2 + ch) * 2 * (LH * Bn);
        St[tid * Bn + b] = s;
        St[LH * Bn + tid * Bn + b] = ss;
    }
}

__global__ __launch_bounds__(192) void k_first(const float* __restrict__ M,
                                               const float* __restrict__ lb,
                                               const float* __restrict__ lv,
                                               const float* __restrict__ hb,
                                               const float* __restrict__ hv,
                                               float* __restrict__ Lg,
                                               float* __restrict__ Stats) {
    int ch = blockIdx.x >> 5, b = blockIdx.x & 31;
    if (ch == 0)
        first_impl<Ll>(0, b, M, lb, lv, Lg, Stats);
    else
        first_impl<LH>(1, b, M, hb, hv, Lg, Stats);
}

// finalize BN(l) -> softmax -> P update -> logits(l+1) + Stats(l+1)
template <int T>
__device__ __forceinline__ void mid_impl(int ch, int b, int l,
                                         const float* __restrict__ M,
                                         const float* __restrict__ bb_all,
                                         const float* __restrict__ v_all,
                                         const float* __restrict__ g_all,
                                         const float* __restrict__ be_all,
                                         float* __restrict__ Lg,
                                         float* __restrict__ Stats,
                                         float* __restrict__ Pws) {
    const int TT = T * T;
    __shared__ float sP[LH * LH], sC[LH * LH], sA[LH * LH], sB[LH * LH], sM[LH * LH];
    __shared__ float sMean[LH], sScale[LH], sShift[LH];
    int tid = threadIdx.x;
    bool first = (l == 0);
    float* Lgb = Lg + (size_t)(ch * Bn + b) * (LH * LH);
    float* Pb = Pws + (size_t)(ch * Bn + b) * (LH * LH);
    if (tid < T) {  // finalize stats of layer l (redundant per block, 832 loads)
        const float* St = Stats + (size_t)(l * 2 + ch) * 2 * (LH * Bn);
        float s = 0.f, ss = 0.f;
        for (int b2 = 0; b2 < Bn; ++b2) {
            s += St[tid * Bn + b2];
            ss += St[LH * Bn + tid * Bn + b2];
        }
        float inv = 1.f / (float)(Bn * T);
        float m = s * inv;
        float var = ss * inv - m * m;
        sMean[tid] = m;
        sScale[tid] = rsqrtf(var + BN_EPS) * g_all[l * T + tid];
        sShift[tid] = be_all[l * T + tid];
    }
    if (tid < TT) {
        sA[tid] = Lgb[tid];
        if (!first) sP[tid] = Pb[tid];
    }
    __syncthreads();
    if (tid < T) {  // softmax row t over q -> coef sC[t][q]
        float vals[T];
        float mx = -1e30f;
#pragma unroll
        for (int q = 0; q < T; ++q) {
            float x = (sA[tid * T + q] - sMean[q]) * sScale[q] + sShift[q];
            vals[q] = x;
            mx = fmaxf(mx, x);
        }
        float sm = 0.f;
#pragma unroll
        for (int q = 0; q < T; ++q) {
            vals[q] = expf(vals[q] - mx);
            sm += vals[q];
        }
        float inv = 1.f / sm;
#pragma unroll
        for (int q = 0; q < T; ++q) sC[tid * T + q] = vals[q] * inv;
    }
    __syncthreads();
    if (tid < TT) {  // Pn[t0][q] = sum_t P[t0][t]*coef[q][t] -> sB
        int t0 = tid / T, q = tid % T;
        float a;
        if (first) {
            a = sC[q * T + t0];
        } else {
            a = 0.f;
#pragma unroll
            for (int t = 0; t < T; ++t) a += sP[t0 * T + t] * sC[q * T + t];
        }
        sB[tid] = a;
        Pb[tid] = a;
    }
    const float* Mn = M + ((size_t)(ch * LAYERS + l + 1) * Bn + b) * (LH * LH);
    for (int i = tid; i < T * LH; i += 192) sM[i] = Mn[i];
    __syncthreads();
    if (tid < TT) {  // S1[t][t1] = sum_t0 Pn[t0][t]*M[t0][t1] -> sA
        int t = tid / T, t1 = tid % T;
        float a = 0.f;
#pragma unroll
        for (int t0 = 0; t0 < T; ++t0) a += sB[t0 * T + t] * sM[t0 * LH + t1];
        sA[tid] = a;
    }
    __syncthreads();
    const float* bbn = bb_all + (size_t)(l + 1) * TT;
    if (tid < TT) {  // scores = sigmoid(bb + S1 @ Pn) -> sP
        int t = tid / T, q = tid % T;
        float a = bbn[tid];
#pragma unroll
        for (int t1 = 0; t1 < T; ++t1) a += sA[t * T + t1] * sB[t1 * T + q];
        sP[tid] = 1.f / (1.f + expf(-a));
    }
    __syncthreads();
    const float* vn = v_all + (size_t)(l + 1) * TT;
    if (tid < TT) {  // logits = v @ scores -> sA + Lg
        int t = tid / T, q = tid % T;
        float a = 0.f;
#pragma unroll
        for (int k = 0; k < T; ++k) a += vn[t * T + k] * sP[k * T + q];
        sA[tid] = a;
        Lgb[tid] = a;
    }
    __syncthreads();
    if (tid < T) {  // Stats(l+1) partials
        float s = 0.f, ss = 0.f;
#pragma unroll
        for (int t = 0; t < T; ++t) {
            float x = sA[t * T + tid];
            s += x;
            ss += x * x;
        }
        float* St = Stats + (size_t)((l + 1) * 2 + ch) * 2 * (LH * Bn);
        St[tid * Bn + b] = s;
        St[LH * Bn + tid * Bn + b] = ss;
    }
}

__global__ __launch_bounds__(192) void k_mid(const float* __restrict__ M,
                                             const float* __restrict__ lb,
                                             const float* __restrict__ lv,
                                             const float* __restrict__ lgam,
                                             const float* __restrict__ lbet,
                                             const float* __restrict__ hb,
                                             const float* __restrict__ hv,
                                             const float* __restrict__ hgam,
                                             const float* __restrict__ hbet,
                                             float* __restrict__ Lg,
                                             float* __restrict__ Stats,
                                             float* __restrict__ Pws, int l) {
    int ch = blockIdx.x >> 5, b = blockIdx.x & 31;
    if (ch == 0)
        mid_impl<Ll>(0, b, l, M, lb, lv, lgam, lbet, Lg, Stats, Pws);
    else
        mid_impl<LH>(1, b, l, M, hb, hv, hgam, hbet, Lg, Stats, Pws);
}

// last layer: finalize BN(3) -> softmax -> P update -> write Pcol
template <int T>
__device__ __forceinline__ void last_impl(int ch, int b,
                                          const float* __restrict__ g_all,
                                          const float* __restrict__ be_all,
                                          const float* __restrict__ Lg,
                                          const float* __restrict__ Stats,
                                          const float* __restrict__ Pws,
                                          float* __restrict__ Pcol) {
    const int TT = T * T;
    const int l = LAYERS - 1;
    __shared__ float sP[LH * LH], sC[LH * LH], sA[LH * LH], sB[LH * LH];
    __shared__ float sMean[LH], sScale[LH], sShift[LH];
    int tid = threadIdx.x;
    const float* Lgb = Lg + (size_t)(ch * Bn + b) * (LH * LH);
    const float* Pb = Pws + (size_t)(ch * Bn + b) * (LH * LH);
    if (tid < T) {
        const float* St = Stats + (size_t)(l * 2 + ch) * 2 * (LH * Bn);
        float s = 0.f, ss = 0.f;
        for (int b2 = 0; b2 < Bn; ++b2) {
            s += St[tid * Bn + b2];
            ss += St[LH * Bn + tid * Bn + b2];
        }
        float inv = 1.f / (float)(Bn * T);
        float m = s * inv;
        float var = ss * inv - m * m;
        sMean[tid] = m;
        sScale[tid] = rsqrtf(var + BN_EPS) * g_all[l * T + tid];
        sShift[tid] = be_all[l * T + tid];
    }
    if (tid < TT) {
        sA[tid] = Lgb[tid];
        sP[tid] = Pb[tid];
    }
    __syncthreads();
    if (tid < T) {
        float vals[T];
        float mx = -1e30f;
#pragma unroll
        for (int q = 0; q < T; ++q) {
            float x = (sA[tid * T + q] - sMean[q]) * sScale[q] + sShift[q];
            vals[q] = x;
            mx = fmaxf(mx, x);
        }
        float sm = 0.f;
#pragma unroll
        for (int q = 0; q < T; ++q) {
            vals[q] = expf(vals[q] - mx);
            sm += vals[q];
        }
        float inv = 1.f / sm;
#pragma unroll
        for (int q = 0; q < T; ++q) sC[tid * T + q] = vals[q] * inv;
    }
    __syncthreads();
    if (tid < TT) {
        int t0 = tid / T, q = tid % T;
        float a = 0.f;
#pragma unroll
        for (int t = 0; t < T; ++t) a += sP[t0 * T + t] * sC[q * T + t];
        sB[tid] = a;
    }
    __syncthreads();
    if (tid < T) Pcol[(size_t)ch * Bn * LH + b * LH + tid] = sB[tid * T + (T - 1)];
}

__global__ __launch_bounds__(192) void k_last(const float* __restrict__ lgam,
                                              const float* __restrict__ lbet,
                                              const float* __restrict__ hgam,
                                              const float* __restrict__ hbet,
                                              const float* __restrict__ Lg,
                                              const float* __restrict__ Stats,
                                              const float* __restrict__ Pws,
                                              float* __restrict__ Pcol) {
    int ch = blockIdx.x >> 5, b = blockIdx.x & 31;
    if (ch == 0)
        last_impl<Ll>(0, b, lgam, lbet, Lg, Stats, Pws, Pcol);
    else
        last_impl<LH>(1, b, hgam, hbet, Lg, Stats, Pws, Pcol);
}

// ---- final: residuals + alpha blend using last-column weights (unchanged) ----
__global__ __launch_bounds__(256) void k_final(const float* __restrict__ XL,
                                               const float* __restrict__ XH,
                                               const float* __restrict__ Pcol,
                                               const float* __restrict__ alpha,
                                               float* __restrict__ out) {
    __shared__ float s_pl[Ll];
    __shared__ float s_ph[LH];
    int b = blockIdx.y;
    int tid = threadIdx.x;
    if (tid < Ll) s_pl[tid] = Pcol[b * LH + tid];
    if (tid < LH) s_ph[tid] = Pcol[Bn * LH + b * LH + tid];
    __syncthreads();
    int cn = blockIdx.x * blockDim.x + tid;
    if (cn >= Cc * Nn) return;
    size_t idx = (size_t)b * Cc * Nn + cn;
    const float* pl = XL + idx * Ll;
    const float* ph = XH + idx * Ll;
    float accL = 0.f, accH = 0.f;
#pragma unroll
    for (int t = 0; t < Ll; ++t) {
        accL += pl[t] * s_pl[t];
        accH += ph[t] * s_ph[t + 1];  // high-channel t0=0 plane is the zero pad
    }
    float a = 1.f / (1.f + expf(-alpha[0]));
    float xl = pl[Ll - 1] + accL;
    float xh = ph[Ll - 1] + accH;
    out[idx] = a * xl + (1.f - a) * xh;
}

extern "C" void kernel_launch(void* const* d_in, const int* in_sizes, int n_in,
                              void* d_out, int out_size, void* d_ws, size_t ws_size,
                              hipStream_t stream) {
    const float* XL = (const float*)d_in[0];
    const float* XH = (const float*)d_in[1];
    const float* lc1 = (const float*)d_in[2];
    const float* lc2 = (const float*)d_in[3];
    const float* lw = (const float*)d_in[4];
    const float* lb = (const float*)d_in[5];
    const float* lv = (const float*)d_in[6];
    const float* lg = (const float*)d_in[7];
    const float* lbeta = (const float*)d_in[8];
    const float* hc1 = (const float*)d_in[9];
    const float* hc2 = (const float*)d_in[10];
    const float* hw = (const float*)d_in[11];
    const float* hb = (const float*)d_in[12];
    const float* hv = (const float*)d_in[13];
    const float* hg = (const float*)d_in[14];
    const float* hbeta = (const float*)d_in[15];
    const float* alpha = (const float*)d_in[16];
    float* out = (float*)d_out;

    float* ws = (float*)d_ws;
    float* G1 = ws;                                          // 2*4*32*13*307
    float* G2 = G1 + (size_t)2 * LAYERS * Bn * LH * Nn;      // 2*4*32*13*128
    float* M = G2 + (size_t)2 * LAYERS * Bn * LH * Cc;       // 2*4*32*13*13
    float* Pcol = M + (size_t)2 * LAYERS * Bn * LH * LH;     // 2*32*13
    float* Stats = Pcol + (size_t)2 * Bn * LH;               // 16*13*32
    float* Lg = Stats + (size_t)4 * LAYERS * LH * Bn;        // 2*32*169
    float* Pws = Lg + (size_t)2 * Bn * LH * LH;              // 2*32*169

    k_g1<<<dim3(10, 32, 2), 256, 0, stream>>>(XL, XH, lc1, hc1, G1);
    k_g2<<<dim3(32, 32, 2), 256, 0, stream>>>(XL, XH, lc2, hc2, G2);
    k_gwm<<<2 * LAYERS * Bn, 256, 0, stream>>>(lw, hw, G1, G2, M);
    k_first<<<64, 192, 0, stream>>>(M, lb, lv, hb, hv, Lg, Stats);
    k_mid<<<64, 192, 0, stream>>>(M, lb, lv, lg, lbeta, hb, hv, hg, hbeta, Lg, Stats, Pws, 0);
    k_mid<<<64, 192, 0, stream>>>(M, lb, lv, lg, lbeta, hb, hv, hg, hbeta, Lg, Stats, Pws, 1);
    k_mid<<<64, 192, 0, stream>>>(M, lb, lv, lg, lbeta, hb, hv, hg, hbeta, Lg, Stats, Pws, 2);
    k_last<<<64, 192, 0, stream>>>(lg, lbeta, hg, hbeta, Lg, Stats, Pws, Pcol);
    k_final<<<dim3((Cc * Nn + 255) / 256, Bn), 256, 0, stream>>>(XL, XH, Pcol, alpha, out);
}